// Round 3
// baseline (450.518 us; speedup 1.0000x reference)
//
#include <hip/hip_runtime.h>
#include <stdint.h>

typedef short bf16x8 __attribute__((ext_vector_type(8)));
typedef float f32x4  __attribute__((ext_vector_type(4)));

#define DEVINL __device__ __forceinline__

static constexpr int Bb = 8, Nn = 8192, Ll = 1024, Dd = 128;
static constexpr int Mm = Bb * Nn;            // 65536 rows
static constexpr int BM = 128, BK = 32, NK = Ll / BK;   // 32 K-steps

// ws layout (bytes)
static constexpr size_t WS_WIMG = 0;          // 2 gates * 32 ksteps * 8192 B = 524288
static constexpr size_t WS_A    = 524288;     // 65536 f32 pre-softmax logits
static constexpr size_t WS_W    = 786432;     // 65536 f32 softmax weights
static constexpr size_t WS_FLAG = 1048576;    // int: mask is 1-byte bool?

DEVINL uint16_t f2bf(float f) {               // RNE float->bf16
  uint32_t u = __builtin_bit_cast(uint32_t, f);
  u += 0x7FFFu + ((u >> 16) & 1u);
  return (uint16_t)(u >> 16);
}
DEVINL float bf2f(uint16_t h) {
  uint32_t u = ((uint32_t)h) << 16;
  return __builtin_bit_cast(float, u);
}
DEVINL uint32_t pk2(float lo, float hi) {
  return (uint32_t)f2bf(lo) | ((uint32_t)f2bf(hi) << 16);
}
DEVINL float fast_tanh(float x) {             // 1 - 2/(e^{2x}+1), ~1e-7 rel
  return 1.0f - 2.0f / (__expf(2.0f * x) + 1.0f);
}
DEVINL float fast_sigmoid(float x) {
  return 1.0f / (1.0f + __expf(-x));
}

// async 16B global->LDS when available; register round-trip fallback has
// identical semantics (dst linear in lane order, src pre-swizzled in global).
#if __has_builtin(__builtin_amdgcn_global_load_lds)
#define G2LDS16(SRC, DST)                                                      \
  __builtin_amdgcn_global_load_lds(                                            \
      (const __attribute__((address_space(1))) uint32_t*)(SRC),                \
      (__attribute__((address_space(3))) uint32_t*)(DST), 16, 0, 0)
#else
#define G2LDS16(SRC, DST) (*(uint4*)(DST) = *(const uint4*)(SRC))
#endif

// ---------------------------------------------------------------------------
// prep W (blocks 0..127): fp32 [K=1024][D=128] -> bf16 tile images: per
// (gate,kstep) an 8 KB image of a [d:128][k:32] transposed tile; 16B chunk c
// of row d holds logical k-chunk q = c ^ ((d>>1)&3) (XOR swizzle).
// Block 128: mask dtype detection. jnp bool is 1 B/elem; if widened to int32,
// bytes at (i&3)!=0 are always 0 (values 0/1). Any nonzero there => bool8.
__global__ void prep_w_k(const float* __restrict__ Wa, const float* __restrict__ Wb,
                         char* __restrict__ wimg, const uint32_t* __restrict__ mraw,
                         int* __restrict__ flag) {
  if (blockIdx.x == 128) {
    __shared__ int s;
    if (threadIdx.x == 0) s = 0;
    __syncthreads();
    int any = 0;
    for (int i = threadIdx.x; i < Mm / 4; i += 256)
      if (mraw[i] & 0xFFFFFF00u) any = 1;
    if (any) s = 1;                            // benign race
    __syncthreads();
    if (threadIdx.x == 0) *flag = s;
    return;
  }
  int ci = blockIdx.x * 256 + threadIdx.x;    // 32768 chunks of 16 B
  int gate = ci >> 14;
  int rem  = ci & 16383;
  int ks   = rem >> 9;                        // 32 tiles per gate
  int t    = rem & 511;                       // chunk within tile
  int d = t >> 2, c = t & 3;
  int q = c ^ ((d >> 1) & 3);                 // logical k-chunk stored here
  const float* W = gate ? Wb : Wa;
  int kbase = ks * BK + q * 8;
  uint4 v;
  v.x = pk2(W[(size_t)(kbase + 0) * Dd + d], W[(size_t)(kbase + 1) * Dd + d]);
  v.y = pk2(W[(size_t)(kbase + 2) * Dd + d], W[(size_t)(kbase + 3) * Dd + d]);
  v.z = pk2(W[(size_t)(kbase + 4) * Dd + d], W[(size_t)(kbase + 5) * Dd + d]);
  v.w = pk2(W[(size_t)(kbase + 6) * Dd + d], W[(size_t)(kbase + 7) * Dd + d]);
  *(uint4*)(wimg + (size_t)ci * 16) = v;
}

DEVINL bool is_pad(const void* mask, int flagv, int idx) {
  return flagv ? (((const uint8_t*)mask)[idx] != 0)
               : (((const int*)mask)[idx] != 0);
}

// ---------------------------------------------------------------------------
// Fused gated-attention logits: A[m] = (tanh(x@Wa) * sigmoid(x@Wb)) @ Wc
// 512 blocks * 256 thr. BM=128 rows, BK=32, double-buffered LDS.
// wid>>1 = row half (64 rows), wid&1 = gate (0:Wa/tanh, 1:Wb/sigmoid).
// Per wave: 4 rowtiles x 8 coltiles of mfma_f32_16x16x32_bf16.
__launch_bounds__(256, 2)
__global__ void gemm_gates_k(const float* __restrict__ x, const char* __restrict__ wimg,
                             const float* __restrict__ Wc, float* __restrict__ Aout,
                             const void* __restrict__ mask, const int* __restrict__ flag) {
  __shared__ __align__(16) char smem[49152];   // 2 bufs * (x 8K | wa 8K | wb 8K)
  __shared__ int s_skip;
  const int tid  = threadIdx.x;
  const int lane = tid & 63;
  const int wid  = tid >> 6;
  const int m0   = blockIdx.x * BM;
  const int l15  = lane & 15;
  const int lq   = lane >> 4;

  // skip fully-padded 128-row chunks (their A is never consumed)
  if (tid == 0) s_skip = 1;
  __syncthreads();
  if (tid < BM) {
    if (!is_pad(mask, *flag, m0 + tid)) s_skip = 0;
  }
  __syncthreads();
  if (s_skip) return;

  const int rw   = wid >> 1;
  const int gate = wid & 1;

  f32x4 acc[4][8] = {};

  // x staging geometry: thread -> (row, 16-float half), swizzled chunk targets
  const int srow = tid >> 1;
  const int sq0  = (tid & 1) * 2;
  const int ssw  = (srow >> 1) & 3;
  const int c0s  = (sq0 ^ ssw) << 4;
  const int c1s  = ((sq0 + 1) ^ ssw) << 4;

  auto stage = [&](int buf, int ks) {
    char* base = smem + buf * 24576;
    // W tiles: pre-swizzled images -> LDS, linear dest (wave-uniform + lane*16)
#pragma unroll
    for (int g = 0; g < 2; ++g) {
      const char* src = wimg + ((size_t)g * NK + ks) * 8192 + (size_t)(wid * 128 + lane) * 16;
      char* dst = base + 8192 + g * 8192 + wid * 2048;
      G2LDS16(src, dst + lane * 16 * 0);       // builtin adds lane*16 itself
      G2LDS16(src + 1024, dst + 1024);
    }
    // x tile: fp32 -> bf16 through registers, swizzled ds_write_b128 x2
    const float4* xs = (const float4*)(x + (size_t)(m0 + srow) * Ll + ks * BK + sq0 * 8);
    float4 v0 = xs[0], v1 = xs[1], v2 = xs[2], v3 = xs[3];
    uint4 p0, p1;
    p0.x = pk2(v0.x, v0.y); p0.y = pk2(v0.z, v0.w);
    p0.z = pk2(v1.x, v1.y); p0.w = pk2(v1.z, v1.w);
    p1.x = pk2(v2.x, v2.y); p1.y = pk2(v2.z, v2.w);
    p1.z = pk2(v3.x, v3.y); p1.w = pk2(v3.z, v3.w);
    *(uint4*)(base + srow * 64 + c0s) = p0;
    *(uint4*)(base + srow * 64 + c1s) = p1;
  };

  stage(0, 0);
  int cur = 0;
#pragma unroll 1
  for (int ks = 0; ks < NK; ++ks) {
    __syncthreads();                    // buf[cur] staged; buf[cur^1] reads done
    if (ks + 1 < NK) stage(cur ^ 1, ks + 1);
    const char* xb = smem + cur * 24576;
    const char* wb = xb + 8192 + gate * 8192;
    bf16x8 a[4];
#pragma unroll
    for (int rt = 0; rt < 4; ++rt) {
      int row = rw * 64 + rt * 16 + l15;
      a[rt] = *(const bf16x8*)(xb + row * 64 + ((lq ^ ((row >> 1) & 3)) << 4));
    }
#pragma unroll
    for (int ct = 0; ct < 8; ++ct) {
      int dr = ct * 16 + l15;
      bf16x8 bfr = *(const bf16x8*)(wb + dr * 64 + ((lq ^ ((dr >> 1) & 3)) << 4));
#pragma unroll
      for (int rt = 0; rt < 4; ++rt)
        acc[rt][ct] = __builtin_amdgcn_mfma_f32_16x16x32_bf16(a[rt], bfr, acc[rt][ct], 0, 0, 0);
    }
    cur ^= 1;
  }
  __syncthreads();                      // staging LDS now reusable

  // epilogue: gate1 waves publish sigmoid(bf16) via LDS [128][132]
  uint16_t* gls = (uint16_t*)smem;
  if (gate == 1) {
#pragma unroll
    for (int rt = 0; rt < 4; ++rt)
#pragma unroll
      for (int ct = 0; ct < 8; ++ct)
#pragma unroll
        for (int r = 0; r < 4; ++r) {
          int row = rw * 64 + rt * 16 + lq * 4 + r;
          int col = ct * 16 + l15;
          gls[row * 132 + col] = f2bf(fast_sigmoid(acc[rt][ct][r]));
        }
  }
  __syncthreads();
  if (gate == 0) {
    float ps[4][4] = {};
#pragma unroll
    for (int ct = 0; ct < 8; ++ct) {
      int col = ct * 16 + l15;
      float wc = Wc[col];
#pragma unroll
      for (int rt = 0; rt < 4; ++rt)
#pragma unroll
        for (int r = 0; r < 4; ++r) {
          int row = rw * 64 + rt * 16 + lq * 4 + r;
          float av = fast_tanh(acc[rt][ct][r]);
          float gv = bf2f(gls[row * 132 + col]);
          ps[rt][r] += av * gv * wc;
        }
    }
#pragma unroll
    for (int rt = 0; rt < 4; ++rt)
#pragma unroll
      for (int r = 0; r < 4; ++r) {
        float v = ps[rt][r];
        v += __shfl_xor(v, 1);
        v += __shfl_xor(v, 2);
        v += __shfl_xor(v, 4);
        v += __shfl_xor(v, 8);
        ps[rt][r] = v;
      }
    if (l15 == 0) {
#pragma unroll
      for (int rt = 0; rt < 4; ++rt)
#pragma unroll
        for (int r = 0; r < 4; ++r)
          Aout[m0 + rw * 64 + rt * 16 + lq * 4 + r] = ps[rt][r];
    }
  }
}

// ---------------------------------------------------------------------------
// masked softmax per bag -> weights (0 where padded); also zeroes out[b,:]
// (d_out is poisoned before every timed launch; wsum accumulates atomically).
__global__ void softmax_k(const float* __restrict__ A, const void* __restrict__ mask,
                          const int* __restrict__ flag, float* __restrict__ wout,
                          float* __restrict__ out) {
  __shared__ float red[16];
  const int b = blockIdx.x;
  const int tid = threadIdx.x;
  const int lane = tid & 63;
  const int wv = tid >> 6;             // 16 waves
  const int fl = *flag;
  out[b * Ll + tid] = 0.f;             // zero this bag's output slice
  float vals[8];
  bool pad[8];
  float mx = -3.0e38f;
#pragma unroll
  for (int j = 0; j < 8; ++j) {
    int idx = b * Nn + j * 1024 + tid;
    bool p = is_pad(mask, fl, idx);
    float v = A[idx];
    pad[j] = p; vals[j] = v;
    if (!p) mx = fmaxf(mx, v);
  }
#pragma unroll
  for (int d = 32; d > 0; d >>= 1) mx = fmaxf(mx, __shfl_xor(mx, d));
  if (lane == 0) red[wv] = mx;
  __syncthreads();
  {
    float t = red[lane & 15];
#pragma unroll
    for (int d = 8; d > 0; d >>= 1) t = fmaxf(t, __shfl_xor(t, d));
    mx = __shfl(t, 0);
  }
  float sum = 0.f;
#pragma unroll
  for (int j = 0; j < 8; ++j) {
    float e = pad[j] ? 0.f : __expf(vals[j] - mx);
    vals[j] = e; sum += e;
  }
#pragma unroll
  for (int d = 32; d > 0; d >>= 1) sum += __shfl_xor(sum, d);
  __syncthreads();                     // red[] reuse
  if (lane == 0) red[wv] = sum;
  __syncthreads();
  {
    float t = red[lane & 15];
#pragma unroll
    for (int d = 8; d > 0; d >>= 1) t += __shfl_xor(t, d);
    sum = __shfl(t, 0);
  }
  float inv = 1.0f / sum;
#pragma unroll
  for (int j = 0; j < 8; ++j)
    wout[b * Nn + j * 1024 + tid] = vals[j] * inv;
}

// ---------------------------------------------------------------------------
// out[b,:] += sum_n w[b,n] * x[b,n,:]  -- 64-way n-split, float4-coalesced
__launch_bounds__(256)
__global__ void wsum_k(const float* __restrict__ x, const float* __restrict__ w,
                       float* __restrict__ out) {
  const int b = blockIdx.y;
  const int s = blockIdx.x;            // 64 chunks of 128 rows
  const int tid = threadIdx.x;
  __shared__ float wl[128];
  __shared__ int anyf;
  const int n0 = s * 128;
  if (tid == 0) anyf = 0;
  __syncthreads();
  if (tid < 128) {
    float v = w[b * Nn + n0 + tid];
    wl[tid] = v;
    if (v != 0.f) anyf = 1;            // benign race
  }
  __syncthreads();
  if (!anyf) return;                   // whole chunk padded -> no traffic
  const float4* xp = (const float4*)(x + ((size_t)b * Nn + n0) * Ll) + tid;
  float4 a0 = {0.f, 0.f, 0.f, 0.f};
  float4 a1 = {0.f, 0.f, 0.f, 0.f};
#pragma unroll 8
  for (int n = 0; n < 128; n += 2) {
    float w0 = wl[n], w1 = wl[n + 1];
    if (w0 != 0.f) {
      float4 v = xp[(size_t)n * 256];
      a0.x += w0 * v.x; a0.y += w0 * v.y; a0.z += w0 * v.z; a0.w += w0 * v.w;
    }
    if (w1 != 0.f) {
      float4 v = xp[(size_t)(n + 1) * 256];
      a1.x += w1 * v.x; a1.y += w1 * v.y; a1.z += w1 * v.z; a1.w += w1 * v.w;
    }
  }
  float* o = out + b * Ll + tid * 4;
  atomicAdd(o + 0, a0.x + a1.x);
  atomicAdd(o + 1, a0.y + a1.y);
  atomicAdd(o + 2, a0.z + a1.z);
  atomicAdd(o + 3, a0.w + a1.w);
}

// ---------------------------------------------------------------------------
extern "C" void kernel_launch(void* const* d_in, const int* in_sizes, int n_in,
                              void* d_out, int out_size, void* d_ws, size_t ws_size,
                              hipStream_t stream) {
  const float* x    = (const float*)d_in[0];
  const void*  mask = d_in[1];
  const float* Wa   = (const float*)d_in[2];
  const float* Wb   = (const float*)d_in[3];
  const float* Wc   = (const float*)d_in[4];
  float* out = (float*)d_out;
  char*  ws  = (char*)d_ws;

  char*  wimg = ws + WS_WIMG;
  float* A    = (float*)(ws + WS_A);
  float* w    = (float*)(ws + WS_W);
  int*   flag = (int*)(ws + WS_FLAG);

  prep_w_k<<<dim3(129), dim3(256), 0, stream>>>(Wa, Wb, wimg, (const uint32_t*)mask, flag);
  gemm_gates_k<<<dim3(Mm / BM), dim3(256), 0, stream>>>(x, wimg, Wc, A, mask, flag);
  softmax_k<<<dim3(Bb), dim3(1024), 0, stream>>>(A, mask, flag, w, out);
  wsum_k<<<dim3(64, Bb), dim3(256), 0, stream>>>(x, w, out);
}